// Round 7
// baseline (174.705 us; speedup 1.0000x reference)
//
#include <hip/hip_runtime.h>
#include <hip/hip_bf16.h>

#define BB 8
#define CC 512
#define NN 1024   // H*W
#define NG 32
#define CPG 16
#define NH 8
#define HD 64
#define C3 1536
#define QKLD 1024  // row length of qkT [n][o2], o2 in [0,1024): Q then K

typedef __hip_bfloat16 bf16;
typedef unsigned short ushort_t;

typedef __attribute__((ext_vector_type(8))) short bf16x8;
typedef __attribute__((ext_vector_type(8))) unsigned short ushortx8;
typedef __attribute__((ext_vector_type(4))) float floatx4;

__device__ __forceinline__ float b2f(bf16 h) { return __bfloat162float(h); }
__device__ __forceinline__ bf16 f2b(float f) { return __float2bfloat16(f); }
__device__ __forceinline__ float us2f(ushort_t u) {
    union { unsigned int i; float f; } c; c.i = ((unsigned int)u) << 16; return c.f;
}
__device__ __forceinline__ ushort_t f2us(float f) {
    bf16 h = __float2bfloat16(f);
    return *(ushort_t*)&h;
}

// ---------------- GroupNorm (blocks 0..255, single global read) + weight f32->bf16
// conversion (blocks 256..271, grid-stride) ----------------
__global__ __launch_bounds__(256) void gn_kernel(const float* __restrict__ x,
                                                 const float* __restrict__ gamma,
                                                 const float* __restrict__ beta,
                                                 bf16* __restrict__ xnT,
                                                 const float* __restrict__ wqkv,
                                                 const float* __restrict__ wproj,
                                                 ushort_t* __restrict__ wqkvB,
                                                 ushort_t* __restrict__ wprojB) {
    int tid = threadIdx.x;
    if (blockIdx.x >= 256) {
        // ---- weight conversion: 16 blocks grid-stride over both matrices ----
        int wb = blockIdx.x - 256;           // 0..15
        int base = (wb * 256 + tid) * 4;
        const int STR = 16 * 256 * 4;        // 16384 floats/pass
        for (int i = base; i < C3 * CC; i += STR) {
            float4 f = *(const float4*)(wqkv + i);
            ushort_t u[4] = {f2us(f.x), f2us(f.y), f2us(f.z), f2us(f.w)};
            *(uint2*)(wqkvB + i) = *(uint2*)u;
        }
        for (int i = base; i < CC * CC; i += STR) {
            float4 f = *(const float4*)(wproj + i);
            ushort_t u[4] = {f2us(f.x), f2us(f.y), f2us(f.z), f2us(f.w)};
            *(uint2*)(wprojB + i) = *(uint2*)u;
        }
        return;
    }

    const int GSZ = CPG * NN;  // 16384, contiguous per group
    int b = blockIdx.x >> 5;
    int g = blockIdx.x & 31;
    size_t base = ((size_t)b * CC + (size_t)g * CPG) * NN;

    int c_loc = tid >> 4;            // 0..15
    int nsp   = (tid & 15) * 16;     // n sub-span
    const float* srcrow = x + base + (size_t)c_loc * NN;

    float fv[4][16];
    float s = 0.f, s2 = 0.f;
#pragma unroll
    for (int nc = 0; nc < 4; ++nc) {
        int nb = nc * 256 + nsp;
        *(float4*)(fv[nc] + 0)  = *(const float4*)(srcrow + nb + 0);
        *(float4*)(fv[nc] + 4)  = *(const float4*)(srcrow + nb + 4);
        *(float4*)(fv[nc] + 8)  = *(const float4*)(srcrow + nb + 8);
        *(float4*)(fv[nc] + 12) = *(const float4*)(srcrow + nb + 12);
#pragma unroll
        for (int j = 0; j < 16; ++j) { float v = fv[nc][j]; s += v; s2 += v * v; }
    }

#pragma unroll
    for (int off = 32; off > 0; off >>= 1) {
        s  += __shfl_down(s, off, 64);
        s2 += __shfl_down(s2, off, 64);
    }
    __shared__ float rs[4], rs2[4], stat[2];
    __shared__ ushort_t Lt[16][264];  // [c][n-chunk 256 + pad]
    int wid = tid >> 6, lane = tid & 63;
    if (lane == 0) { rs[wid] = s; rs2[wid] = s2; }
    __syncthreads();
    if (tid == 0) {
        float ts  = rs[0] + rs[1] + rs[2] + rs[3];
        float ts2 = rs2[0] + rs2[1] + rs2[2] + rs2[3];
        float mean = ts * (1.f / GSZ);
        float var  = ts2 * (1.f / GSZ) - mean * mean;
        stat[0] = mean;
        stat[1] = rsqrtf(var + 1e-5f);
    }
    __syncthreads();
    float mean = stat[0], inv = stat[1];

    float ga = gamma[g * CPG + c_loc];
    float be = beta[g * CPG + c_loc];

    for (int nc = 0; nc < 4; ++nc) {
        ushortx8 u0, u1;
#pragma unroll
        for (int j = 0; j < 8; ++j) {
            u0[j] = f2us((fv[nc][j]     - mean) * inv * ga + be);
            u1[j] = f2us((fv[nc][j + 8] - mean) * inv * ga + be);
        }
        *(ushortx8*)&Lt[c_loc][nsp]     = u0;
        *(ushortx8*)&Lt[c_loc][nsp + 8] = u1;
        __syncthreads();
        ushort_t o16[16];
#pragma unroll
        for (int c = 0; c < 16; ++c) o16[c] = Lt[c][tid];
        ushort_t* dst = (ushort_t*)xnT + ((size_t)b * NN + nc * 256 + tid) * CC + g * CPG;
        *(uint4*)dst       = *(const uint4*)(o16);
        *(uint4*)(dst + 8) = *(const uint4*)(o16 + 8);
        __syncthreads();
    }
}

// ---------------- QKV GEMM (MFMA): 128x128 tile, BK=32, register-prefetched K-loop.
// Round-6 structure byte-identical EXCEPT: W staged as pre-converted bf16 (uint4 copies,
// no f32 loads / no cvt chain in the hot loop). Store epilogue untouched.
// Q,K rows (o<1024): transposed store into qkT with Q pre-scaled by log2(e)/8.
// V rows (o>=1024): natural store into vN[b][c][n].
#define GSTR 40
__global__ __launch_bounds__(256) void qkv_gemm(const ushort_t* __restrict__ wB,
                                                const bf16* __restrict__ xnT,
                                                const float* __restrict__ bias,
                                                bf16* __restrict__ qkT,
                                                bf16* __restrict__ vN) {
    __shared__ ushort_t Wl[128 * GSTR];  // [o][k]
    __shared__ ushort_t Xl[128 * GSTR];  // [n][k]
    int b  = blockIdx.z;
    int o0 = blockIdx.y * 128;
    int n0 = blockIdx.x * 128;
    int tid = threadIdx.x;
    int wv = tid >> 6, ln = tid & 15, qd = (tid >> 4) & 3;
    int wm = wv >> 1, wn = wv & 1;

    int srow = tid >> 1;
    int kh   = (tid & 1) * 16;
    const ushort_t* wp = wB + (size_t)(o0 + srow) * CC + kh;
    const ushort_t* xp = (const ushort_t*)xnT + ((size_t)b * NN + n0 + srow) * CC + kh;

    floatx4 acc[4][4];
#pragma unroll
    for (int i = 0; i < 4; ++i)
#pragma unroll
        for (int j = 0; j < 4; ++j) acc[i][j] = (floatx4){0.f, 0.f, 0.f, 0.f};

    uint4 wr0, wr1, xr0, xr1;
    // preload k0 = 0
    wr0 = *(const uint4*)(wp);
    wr1 = *(const uint4*)(wp + 8);
    xr0 = *(const uint4*)(xp);
    xr1 = *(const uint4*)(xp + 8);

    for (int k0 = 0; k0 < CC; k0 += 32) {
        *(uint4*)&Wl[srow * GSTR + kh]     = wr0;
        *(uint4*)&Wl[srow * GSTR + kh + 8] = wr1;
        *(uint4*)&Xl[srow * GSTR + kh]     = xr0;
        *(uint4*)&Xl[srow * GSTR + kh + 8] = xr1;
        __syncthreads();
        if (k0 + 32 < CC) {
            int kn = k0 + 32;
            wr0 = *(const uint4*)(wp + kn);
            wr1 = *(const uint4*)(wp + kn + 8);
            xr0 = *(const uint4*)(xp + kn);
            xr1 = *(const uint4*)(xp + kn + 8);
        }
        bf16x8 af[4], bfr[4];
#pragma unroll
        for (int i = 0; i < 4; ++i)
            af[i] = *(const bf16x8*)&Wl[(wm * 64 + i * 16 + ln) * GSTR + qd * 8];
#pragma unroll
        for (int j = 0; j < 4; ++j)
            bfr[j] = *(const bf16x8*)&Xl[(wn * 64 + j * 16 + ln) * GSTR + qd * 8];
#pragma unroll
        for (int i = 0; i < 4; ++i)
#pragma unroll
            for (int j = 0; j < 4; ++j)
                acc[i][j] = __builtin_amdgcn_mfma_f32_16x16x32_bf16(af[i], bfr[j], acc[i][j], 0, 0, 0);
        __syncthreads();
    }

    if (o0 < 1024) {
        // Q/K tile: transposed packed store, Q scaled by log2(e)/8 (uniform per i-subtile)
#pragma unroll
        for (int i = 0; i < 4; ++i) {
            int ob = o0 + wm * 64 + i * 16 + qd * 4;
            float sc = (ob < 512) ? 0.18033688011112042f : 1.0f;  // 0.125 * log2(e)
#pragma unroll
            for (int j = 0; j < 4; ++j) {
                int n = n0 + wn * 64 + j * 16 + ln;
                ushort_t pk[4];
#pragma unroll
                for (int r = 0; r < 4; ++r)
                    pk[r] = f2us((acc[i][j][r] + bias[ob + r]) * sc);
                *(uint2*)((ushort_t*)qkT + ((size_t)b * NN + n) * QKLD + ob) = *(uint2*)pk;
            }
        }
    } else {
        // V tile: natural [c][n] store
#pragma unroll
        for (int i = 0; i < 4; ++i) {
#pragma unroll
            for (int r = 0; r < 4; ++r) {
                int o = o0 + wm * 64 + i * 16 + qd * 4 + r;
                float bb = bias[o];
                size_t rb = ((size_t)b * CC + (o - 1024)) * NN + n0 + wn * 64 + ln;
#pragma unroll
                for (int j = 0; j < 4; ++j)
                    vN[rb + j * 16] = f2b(acc[i][j][r] + bb);
            }
        }
    }
}

// ---------------- Flash attention: one block per (h, 64-query tile, b) ----------------
// K/V staged in LDS once per block (shared by all 4 waves), XOR-swizzled granules.
// Double-buffered K/V + 2-step register prefetch => ONE barrier per step.
// P transpose buffer [16][64] per wave, same granule swizzle. Total LDS = 40960 B.
// Row-sum via MFMA with ones-fragment; exp2 (Q pre-scaled by log2e/8 in qkv_gemm).
__global__ __launch_bounds__(256, 4) void attn_kernel(const bf16* __restrict__ qkTp,
                                                      const bf16* __restrict__ vNp,
                                                      bf16* __restrict__ aoT) {
    __shared__ ushort_t Kt[2][64 * 64];   // [buf][key][ch]  (swizzled granules)
    __shared__ ushort_t Vn[2][64 * 64];   // [buf][ch][key]  (swizzled granules)
    __shared__ ushort_t Pw[4][16 * 64];   // per-wave [q][key] (swizzled granules)

    int h  = blockIdx.x;        // head (XCD affinity: blockid%8 == h)
    int qt = blockIdx.y;        // query tile 0..15
    int bi = blockIdx.z;
    int q0 = qt * 64;
    int tid = threadIdx.x;
    int wq = tid >> 6;          // wave id: owns queries wq*16..+15
    int l  = tid & 63;
    int ln = l & 15;
    int qd = (l >> 4) & 3;      // quad
    int l7 = ln & 7;
    int lb = ln >> 3;           // 0/1

    const ushort_t* qkT = (const ushort_t*)qkTp;
    const ushort_t* vN  = (const ushort_t*)vNp;

    // ---- per-wave Q A-frags from global (row q = wq*16+ln, k = ch qd*8+j) ----
    const ushort_t* qsrc = qkT + ((size_t)bi * NN + q0 + wq * 16 + ln) * QKLD + h * HD + qd * 8;
    bf16x8 aq0 = *(const bf16x8*)(qsrc);
    bf16x8 aq1 = *(const bf16x8*)(qsrc + 32);

    bf16x8 ones;
#pragma unroll
    for (int j = 0; j < 8; ++j) ones[j] = (short)0x3F80;  // bf16 1.0

    floatx4 O[4];
#pragma unroll
    for (int t = 0; t < 4; ++t) O[t] = (floatx4){0.f, 0.f, 0.f, 0.f};
    floatx4 lsum = (floatx4){0.f, 0.f, 0.f, 0.f};

    ushort_t* Pme = &Pw[wq][0];

    // swizzled fragment-read granule offsets (row&7 == ln&7 since rows are t*16+ln)
    int ksl0 = (qd ^ l7) * 8;
    int ksl1 = ((qd + 4) ^ l7) * 8;

    // ---- staging: 256 threads, each 2x16B per array per tile ----
    int srow = tid >> 2;            // 0..63 (key row for K, ch row for V)
    int g1   = tid & 3;             // granules g1, g1+4
    int s7   = srow & 7;
    int ko1  = (g1 ^ s7) * 8;
    int ko2  = ((g1 + 4) ^ s7) * 8;
    const ushort_t* ks = qkT + ((size_t)bi * NN + srow) * QKLD + 512 + h * HD + g1 * 8;
    const ushort_t* vs = vN + ((size_t)bi * CC + h * HD + srow) * NN + g1 * 8;

    // tile 0 load + write buf0
    uint4 kr0 = *(const uint4*)(ks);
    uint4 kr1 = *(const uint4*)(ks + 32);
    uint4 vr0 = *(const uint4*)(vs);
    uint4 vr1 = *(const uint4*)(vs + 32);
    {
        ushort_t* kd = &Kt[0][srow * 64];
        *(uint4*)(kd + ko1) = kr0; *(uint4*)(kd + ko2) = kr1;
        ushort_t* vd = &Vn[0][srow * 64];
        *(uint4*)(vd + ko1) = vr0; *(uint4*)(vd + ko2) = vr1;
    }
    // prefetch tile 1
    kr0 = *(const uint4*)(ks + (size_t)64 * QKLD);
    kr1 = *(const uint4*)(ks + (size_t)64 * QKLD + 32);
    vr0 = *(const uint4*)(vs + 64);
    vr1 = *(const uint4*)(vs + 64 + 32);
    __syncthreads();

    for (int it = 0; it < 16; ++it) {
        int cur = it & 1;
        const ushort_t* KtC = &Kt[cur][0];
        const ushort_t* VnC = &Vn[cur][0];
        // ---- write tile it+1 into buf cur^1 (its readers finished before last barrier) ----
        if (it < 15) {
            ushort_t* kd = &Kt[cur ^ 1][srow * 64];
            *(uint4*)(kd + ko1) = kr0; *(uint4*)(kd + ko2) = kr1;
            ushort_t* vd = &Vn[cur ^ 1][srow * 64];
            *(uint4*)(vd + ko1) = vr0; *(uint4*)(vd + ko2) = vr1;
        }
        // ---- issue global loads for tile it+2 (2-step prefetch distance) ----
        if (it < 14) {
            size_t mo = (size_t)(it + 2) * 64;
            kr0 = *(const uint4*)(ks + mo * QKLD);
            kr1 = *(const uint4*)(ks + mo * QKLD + 32);
            vr0 = *(const uint4*)(vs + mo);
            vr1 = *(const uint4*)(vs + mo + 32);
        }

        // ---- S = Q^T K : 4 col-tiles of 16 keys, frags from swizzled LDS ----
        floatx4 S[4];
#pragma unroll
        for (int t = 0; t < 4; ++t) {
            const ushort_t* krow = KtC + (t * 16 + ln) * 64;
            bf16x8 b0 = *(const bf16x8*)(krow + ksl0);
            bf16x8 b1 = *(const bf16x8*)(krow + ksl1);
            floatx4 acc = (floatx4){0.f, 0.f, 0.f, 0.f};
            acc = __builtin_amdgcn_mfma_f32_16x16x32_bf16(aq0, b0, acc, 0, 0, 0);
            acc = __builtin_amdgcn_mfma_f32_16x16x32_bf16(aq1, b1, acc, 0, 0, 0);
            S[t] = acc;
        }

        // ---- softmax (no-max; exp2) + swizzled P transpose write ----
#pragma unroll
        for (int t = 0; t < 4; ++t) {
#pragma unroll
            for (int r = 0; r < 4; ++r) {
                float p = exp2f(S[t][r]);
                int qr = qd * 4 + r;
                Pme[qr * 64 + ((t * 2 + lb) ^ (qr & 7)) * 8 + l7] = f2us(p);
            }
        }
        bf16x8 pa0 = *(const bf16x8*)&Pme[ln * 64 + ksl0];
        bf16x8 pa1 = *(const bf16x8*)&Pme[ln * 64 + ksl1];

        // ---- row-sum of P via MFMA with ones (D row = qd*4+r matches epilogue) ----
        lsum = __builtin_amdgcn_mfma_f32_16x16x32_bf16(pa0, ones, lsum, 0, 0, 0);
        lsum = __builtin_amdgcn_mfma_f32_16x16x32_bf16(pa1, ones, lsum, 0, 0, 0);

        // ---- O += P * V^T, V frags from swizzled LDS ----
#pragma unroll
        for (int t = 0; t < 4; ++t) {
            const ushort_t* vrow = VnC + (t * 16 + ln) * 64;
            bf16x8 v0 = *(const bf16x8*)(vrow + ksl0);
            bf16x8 v1 = *(const bf16x8*)(vrow + ksl1);
            O[t] = __builtin_amdgcn_mfma_f32_16x16x32_bf16(pa0, v0, O[t], 0, 0, 0);
            O[t] = __builtin_amdgcn_mfma_f32_16x16x32_bf16(pa1, v1, O[t], 0, 0, 0);
        }
        if (it < 15) __syncthreads();
    }

    // ---- epilogue: normalize, direct store to aoT[b][n][c] (O natural layout) ----
    float inv[4];
#pragma unroll
    for (int r = 0; r < 4; ++r) inv[r] = 1.f / lsum[r];
#pragma unroll
    for (int t = 0; t < 4; ++t) {
#pragma unroll
        for (int r = 0; r < 4; ++r) {
            int n = q0 + wq * 16 + qd * 4 + r;
            ((ushort_t*)aoT)[((size_t)bi * NN + n) * CC + h * HD + t * 16 + ln] =
                f2us(O[t][r] * inv[r]);
        }
    }
}

// ---------------- Proj GEMM (MFMA) + bias + residual: 64x128 tile, 512 blocks.
// Round-6 structure byte-identical EXCEPT: W staged as pre-converted bf16.
__global__ __launch_bounds__(256) void proj_gemm(const bf16* __restrict__ aoT,
                                                 const ushort_t* __restrict__ wB,
                                                 const float* __restrict__ bias,
                                                 const float* __restrict__ xres,
                                                 float* __restrict__ out) {
    __shared__ ushort_t Wl[64 * GSTR];   // [c_out][k]
    __shared__ ushort_t Xl[128 * GSTR];  // [n][k]
    int b  = blockIdx.z;
    int o0 = blockIdx.y * 64;
    int n0 = blockIdx.x * 128;
    int tid = threadIdx.x;
    int wv = tid >> 6, ln = tid & 15, qd = (tid >> 4) & 3;
    int wm = wv >> 1, wn = wv & 1;

    int srow = tid >> 1;          // X: 0..127
    int kh   = (tid & 1) * 16;
    const ushort_t* xp = (const ushort_t*)aoT + ((size_t)b * NN + n0 + srow) * CC + kh;
    const ushort_t* wp = wB + (size_t)(o0 + (srow & 63)) * CC + kh;   // W: threads <128 stage
    bool doW = (tid < 128);

    floatx4 acc[2][4];
#pragma unroll
    for (int i = 0; i < 2; ++i)
#pragma unroll
        for (int j = 0; j < 4; ++j) acc[i][j] = (floatx4){0.f, 0.f, 0.f, 0.f};

    uint4 wr0, wr1, xr0, xr1;
    if (doW) {
        wr0 = *(const uint4*)(wp);
        wr1 = *(const uint4*)(wp + 8);
    }
    xr0 = *(const uint4*)(xp);
    xr1 = *(const uint4*)(xp + 8);

    for (int k0 = 0; k0 < CC; k0 += 32) {
        if (doW) {
            *(uint4*)&Wl[(srow & 63) * GSTR + kh]     = wr0;
            *(uint4*)&Wl[(srow & 63) * GSTR + kh + 8] = wr1;
        }
        *(uint4*)&Xl[srow * GSTR + kh]     = xr0;
        *(uint4*)&Xl[srow * GSTR + kh + 8] = xr1;
        __syncthreads();
        if (k0 + 32 < CC) {
            int kn = k0 + 32;
            if (doW) {
                wr0 = *(const uint4*)(wp + kn);
                wr1 = *(const uint4*)(wp + kn + 8);
            }
            xr0 = *(const uint4*)(xp + kn);
            xr1 = *(const uint4*)(xp + kn + 8);
        }
        bf16x8 af[2], bfr[4];
#pragma unroll
        for (int i = 0; i < 2; ++i)
            af[i] = *(const bf16x8*)&Wl[(wm * 32 + i * 16 + ln) * GSTR + qd * 8];
#pragma unroll
        for (int j = 0; j < 4; ++j)
            bfr[j] = *(const bf16x8*)&Xl[(wn * 64 + j * 16 + ln) * GSTR + qd * 8];
#pragma unroll
        for (int i = 0; i < 2; ++i)
#pragma unroll
            for (int j = 0; j < 4; ++j)
                acc[i][j] = __builtin_amdgcn_mfma_f32_16x16x32_bf16(af[i], bfr[j], acc[i][j], 0, 0, 0);
        __syncthreads();
    }

#pragma unroll
    for (int i = 0; i < 2; ++i) {
#pragma unroll
        for (int r = 0; r < 4; ++r) {
            int o = o0 + wm * 32 + i * 16 + qd * 4 + r;
            float bb = bias[o];
            size_t rb = ((size_t)b * CC + o) * NN + n0 + wn * 64 + ln;
#pragma unroll
            for (int j = 0; j < 4; ++j)
                out[rb + j * 16] = acc[i][j][r] + bb + xres[rb + j * 16];
        }
    }
}

extern "C" void kernel_launch(void* const* d_in, const int* in_sizes, int n_in,
                              void* d_out, int out_size, void* d_ws, size_t ws_size,
                              hipStream_t stream) {
    const float* x      = (const float*)d_in[0];
    const float* gamma  = (const float*)d_in[1];
    const float* beta   = (const float*)d_in[2];
    const float* w_qkv  = (const float*)d_in[3];
    const float* b_qkv  = (const float*)d_in[4];
    const float* w_proj = (const float*)d_in[5];
    const float* b_proj = (const float*)d_in[6];
    float* out = (float*)d_out;

    // Workspace (bf16): xnT 8 MB | qkT 16 MB | vN 8 MB | wqkvB 1.5 MB | wprojB 0.5 MB.
    bf16* xnT = (bf16*)d_ws;                       // [b][n][c]
    bf16* qkT = xnT + (size_t)BB * CC * NN;        // [b][n][1024] (Q|K)
    bf16* vN  = qkT + (size_t)BB * NN * QKLD;      // [b][c][n]
    ushort_t* wqkvB  = (ushort_t*)(vN + (size_t)BB * CC * NN);  // [1536][512] bf16
    ushort_t* wprojB = wqkvB + (size_t)C3 * CC;                 // [512][512] bf16
    bf16* aoT = xnT;                               // [b][n][c], reuse

    gn_kernel<<<BB * NG + 16, 256, 0, stream>>>(x, gamma, beta, xnT,
                                                w_qkv, w_proj, wqkvB, wprojB);
    qkv_gemm<<<dim3(NN / 128, C3 / 128, BB), 256, 0, stream>>>(wqkvB, xnT, b_qkv, qkT, vN);
    attn_kernel<<<dim3(NH, NN / 64, BB), 256, 0, stream>>>(qkT, vN, aoT);
    proj_gemm<<<dim3(NN / 128, CC / 64, BB), 256, 0, stream>>>(aoT, wprojB, b_proj, x, out);
}

// Round 8
// 162.964 us; speedup vs baseline: 1.0720x; 1.0720x over previous
//
#include <hip/hip_runtime.h>
#include <hip/hip_bf16.h>

#define BB 8
#define CC 512
#define NN 1024   // H*W
#define NG 32
#define CPG 16
#define NH 8
#define HD 64
#define C3 1536
#define QKLD 1024  // row length of qkT [n][o2], o2 in [0,1024): Q then K

typedef __hip_bfloat16 bf16;
typedef unsigned short ushort_t;

typedef __attribute__((ext_vector_type(8))) short bf16x8;
typedef __attribute__((ext_vector_type(8))) unsigned short ushortx8;
typedef __attribute__((ext_vector_type(4))) float floatx4;

__device__ __forceinline__ float b2f(bf16 h) { return __bfloat162float(h); }
__device__ __forceinline__ bf16 f2b(float f) { return __float2bfloat16(f); }
__device__ __forceinline__ ushort_t f2us(float f) {
    bf16 h = __float2bfloat16(f);
    return *(ushort_t*)&h;
}

// global_load_lds width=16: gsrc per-lane global addr; ldst wave-uniform LDS base,
// HW writes ldst + lane*16. Both casts are addrspace casts (flat->AS1/AS3).
#define GLD16(gsrc, ldst)                                                        \
    __builtin_amdgcn_global_load_lds(                                            \
        (const __attribute__((address_space(1))) unsigned int*)(const void*)(gsrc), \
        (__attribute__((address_space(3))) unsigned int*)(void*)(ldst), 16, 0, 0)

// ---------------- GroupNorm (blocks 0..255, single global read) + weight f32->bf16
// conversion (blocks 256..511: one 4096-float chunk each, fully parallel) ----------------
__global__ __launch_bounds__(256) void gn_kernel(const float* __restrict__ x,
                                                 const float* __restrict__ gamma,
                                                 const float* __restrict__ beta,
                                                 bf16* __restrict__ xnT,
                                                 const float* __restrict__ wqkv,
                                                 const float* __restrict__ wproj,
                                                 ushort_t* __restrict__ wqkvB,
                                                 ushort_t* __restrict__ wprojB) {
    int tid = threadIdx.x;
    if (blockIdx.x >= 256) {
        // 192 blocks -> wqkv (192*4096 = 786432 = C3*CC), 64 blocks -> wproj (64*4096 = CC*CC)
        int wb = blockIdx.x - 256;
        const float* src;
        ushort_t* dst;
        int base;
        if (wb < 192) { src = wqkv; dst = wqkvB; base = wb * 4096; }
        else          { src = wproj; dst = wprojB; base = (wb - 192) * 4096; }
        int o = base + tid * 4;
#pragma unroll
        for (int it = 0; it < 4; ++it) {
            float4 f = *(const float4*)(src + o + it * 1024);
            ushort_t u[4] = {f2us(f.x), f2us(f.y), f2us(f.z), f2us(f.w)};
            *(uint2*)(dst + o + it * 1024) = *(uint2*)u;
        }
        return;
    }

    const int GSZ = CPG * NN;  // 16384, contiguous per group
    int b = blockIdx.x >> 5;
    int g = blockIdx.x & 31;
    size_t base = ((size_t)b * CC + (size_t)g * CPG) * NN;

    int c_loc = tid >> 4;            // 0..15
    int nsp   = (tid & 15) * 16;     // n sub-span
    const float* srcrow = x + base + (size_t)c_loc * NN;

    float fv[4][16];
    float s = 0.f, s2 = 0.f;
#pragma unroll
    for (int nc = 0; nc < 4; ++nc) {
        int nb = nc * 256 + nsp;
        *(float4*)(fv[nc] + 0)  = *(const float4*)(srcrow + nb + 0);
        *(float4*)(fv[nc] + 4)  = *(const float4*)(srcrow + nb + 4);
        *(float4*)(fv[nc] + 8)  = *(const float4*)(srcrow + nb + 8);
        *(float4*)(fv[nc] + 12) = *(const float4*)(srcrow + nb + 12);
#pragma unroll
        for (int j = 0; j < 16; ++j) { float v = fv[nc][j]; s += v; s2 += v * v; }
    }

#pragma unroll
    for (int off = 32; off > 0; off >>= 1) {
        s  += __shfl_down(s, off, 64);
        s2 += __shfl_down(s2, off, 64);
    }
    __shared__ float rs[4], rs2[4], stat[2];
    __shared__ ushort_t Lt[16][264];  // [c][n-chunk 256 + pad]
    int wid = tid >> 6, lane = tid & 63;
    if (lane == 0) { rs[wid] = s; rs2[wid] = s2; }
    __syncthreads();
    if (tid == 0) {
        float ts  = rs[0] + rs[1] + rs[2] + rs[3];
        float ts2 = rs2[0] + rs2[1] + rs2[2] + rs2[3];
        float mean = ts * (1.f / GSZ);
        float var  = ts2 * (1.f / GSZ) - mean * mean;
        stat[0] = mean;
        stat[1] = rsqrtf(var + 1e-5f);
    }
    __syncthreads();
    float mean = stat[0], inv = stat[1];

    float ga = gamma[g * CPG + c_loc];
    float be = beta[g * CPG + c_loc];

    for (int nc = 0; nc < 4; ++nc) {
        ushortx8 u0, u1;
#pragma unroll
        for (int j = 0; j < 8; ++j) {
            u0[j] = f2us((fv[nc][j]     - mean) * inv * ga + be);
            u1[j] = f2us((fv[nc][j + 8] - mean) * inv * ga + be);
        }
        *(ushortx8*)&Lt[c_loc][nsp]     = u0;
        *(ushortx8*)&Lt[c_loc][nsp + 8] = u1;
        __syncthreads();
        ushort_t o16[16];
#pragma unroll
        for (int c = 0; c < 16; ++c) o16[c] = Lt[c][tid];
        ushort_t* dst = (ushort_t*)xnT + ((size_t)b * NN + nc * 256 + tid) * CC + g * CPG;
        *(uint4*)dst       = *(const uint4*)(o16);
        *(uint4*)(dst + 8) = *(const uint4*)(o16 + 8);
        __syncthreads();
    }
}

// ---------------- QKV GEMM: 128x128 tile, BK=32, global_load_lds staging (m97 rung).
// LDS linear [row][32] (64B rows); per-lane global SOURCE pre-swizzled granule^(row&3),
// fragment reads at granule qd^(ln&3)  -> 4-way max bank aliasing.
// MFMA loop and store epilogue byte-identical to round 6/7 (WRITE_SIZE tripwire).
__global__ __launch_bounds__(256) void qkv_gemm(const ushort_t* __restrict__ wB,
                                                const bf16* __restrict__ xnT,
                                                const float* __restrict__ bias,
                                                bf16* __restrict__ qkT,
                                                bf16* __restrict__ vN) {
    __shared__ ushort_t Wl[128 * 32];  // [o][k] linear, 8 KB
    __shared__ ushort_t Xl[128 * 32];  // [n][k] linear, 8 KB
    int b  = blockIdx.z;
    int o0 = blockIdx.y * 128;
    int n0 = blockIdx.x * 128;
    int tid = threadIdx.x;
    int wv = tid >> 6, l = tid & 63, ln = l & 15, qd = (l >> 4) & 3;
    int wm = wv >> 1, wn = wv & 1;

    // staging: wave wv stages rows [32wv, 32wv+32) of each array, 2 DMA calls of 16 rows.
    int strow = wv * 32 + (l >> 2);          // call-0 row; call-1 adds 16
    int sgran = (l & 3) ^ ((l >> 2) & 3);    // source granule pre-swizzle (row&3 == (l>>2)&3)
    const ushort_t* wsrc = wB + (size_t)(o0 + strow) * CC + sgran * 8;
    const ushort_t* xsrc = (const ushort_t*)xnT + ((size_t)b * NN + n0 + strow) * CC + sgran * 8;
    ushort_t* wl0 = &Wl[(wv * 32) * 32];
    ushort_t* wl1 = &Wl[(wv * 32 + 16) * 32];
    ushort_t* xl0 = &Xl[(wv * 32) * 32];
    ushort_t* xl1 = &Xl[(wv * 32 + 16) * 32];

    floatx4 acc[4][4];
#pragma unroll
    for (int i = 0; i < 4; ++i)
#pragma unroll
        for (int j = 0; j < 4; ++j) acc[i][j] = (floatx4){0.f, 0.f, 0.f, 0.f};

    int qs = (qd ^ (ln & 3)) * 8;            // swizzled fragment granule offset

    for (int k0 = 0; k0 < CC; k0 += 32) {
        GLD16(wsrc + k0, wl0);
        GLD16(wsrc + k0 + 16 * CC, wl1);
        GLD16(xsrc + k0, xl0);
        GLD16(xsrc + k0 + 16 * CC, xl1);
        __syncthreads();   // drains vmcnt -> DMA complete
        bf16x8 af[4], bfr[4];
#pragma unroll
        for (int i = 0; i < 4; ++i)
            af[i] = *(const bf16x8*)&Wl[(wm * 64 + i * 16 + ln) * 32 + qs];
#pragma unroll
        for (int j = 0; j < 4; ++j)
            bfr[j] = *(const bf16x8*)&Xl[(wn * 64 + j * 16 + ln) * 32 + qs];
#pragma unroll
        for (int i = 0; i < 4; ++i)
#pragma unroll
            for (int j = 0; j < 4; ++j)
                acc[i][j] = __builtin_amdgcn_mfma_f32_16x16x32_bf16(af[i], bfr[j], acc[i][j], 0, 0, 0);
        __syncthreads();
    }

    if (o0 < 1024) {
        // Q/K tile: transposed packed store, Q scaled by log2(e)/8 (uniform per i-subtile)
#pragma unroll
        for (int i = 0; i < 4; ++i) {
            int ob = o0 + wm * 64 + i * 16 + qd * 4;
            float sc = (ob < 512) ? 0.18033688011112042f : 1.0f;  // 0.125 * log2(e)
#pragma unroll
            for (int j = 0; j < 4; ++j) {
                int n = n0 + wn * 64 + j * 16 + ln;
                ushort_t pk[4];
#pragma unroll
                for (int r = 0; r < 4; ++r)
                    pk[r] = f2us((acc[i][j][r] + bias[ob + r]) * sc);
                *(uint2*)((ushort_t*)qkT + ((size_t)b * NN + n) * QKLD + ob) = *(uint2*)pk;
            }
        }
    } else {
        // V tile: natural [c][n] store
#pragma unroll
        for (int i = 0; i < 4; ++i) {
#pragma unroll
            for (int r = 0; r < 4; ++r) {
                int o = o0 + wm * 64 + i * 16 + qd * 4 + r;
                float bb = bias[o];
                size_t rb = ((size_t)b * CC + (o - 1024)) * NN + n0 + wn * 64 + ln;
#pragma unroll
                for (int j = 0; j < 4; ++j)
                    vN[rb + j * 16] = f2b(acc[i][j][r] + bb);
            }
        }
    }
}

// ---------------- Flash attention: one block per (h, 64-query tile, b) ----------------
// (unchanged from round 6/7: LDS-staged K/V with XOR-swizzled granules, 1 barrier/step,
//  MFMA ones-fragment row-sum, exp2 with pre-scaled Q, 40960 B LDS)
__global__ __launch_bounds__(256, 4) void attn_kernel(const bf16* __restrict__ qkTp,
                                                      const bf16* __restrict__ vNp,
                                                      bf16* __restrict__ aoT) {
    __shared__ ushort_t Kt[2][64 * 64];   // [buf][key][ch]  (swizzled granules)
    __shared__ ushort_t Vn[2][64 * 64];   // [buf][ch][key]  (swizzled granules)
    __shared__ ushort_t Pw[4][16 * 64];   // per-wave [q][key] (swizzled granules)

    int h  = blockIdx.x;        // head (XCD affinity: blockid%8 == h)
    int qt = blockIdx.y;        // query tile 0..15
    int bi = blockIdx.z;
    int q0 = qt * 64;
    int tid = threadIdx.x;
    int wq = tid >> 6;          // wave id: owns queries wq*16..+15
    int l  = tid & 63;
    int ln = l & 15;
    int qd = (l >> 4) & 3;      // quad
    int l7 = ln & 7;
    int lb = ln >> 3;           // 0/1

    const ushort_t* qkT = (const ushort_t*)qkTp;
    const ushort_t* vN  = (const ushort_t*)vNp;

    const ushort_t* qsrc = qkT + ((size_t)bi * NN + q0 + wq * 16 + ln) * QKLD + h * HD + qd * 8;
    bf16x8 aq0 = *(const bf16x8*)(qsrc);
    bf16x8 aq1 = *(const bf16x8*)(qsrc + 32);

    bf16x8 ones;
#pragma unroll
    for (int j = 0; j < 8; ++j) ones[j] = (short)0x3F80;  // bf16 1.0

    floatx4 O[4];
#pragma unroll
    for (int t = 0; t < 4; ++t) O[t] = (floatx4){0.f, 0.f, 0.f, 0.f};
    floatx4 lsum = (floatx4){0.f, 0.f, 0.f, 0.f};

    ushort_t* Pme = &Pw[wq][0];

    int ksl0 = (qd ^ l7) * 8;
    int ksl1 = ((qd + 4) ^ l7) * 8;

    int srow = tid >> 2;            // 0..63
    int g1   = tid & 3;             // granules g1, g1+4
    int s7   = srow & 7;
    int ko1  = (g1 ^ s7) * 8;
    int ko2  = ((g1 + 4) ^ s7) * 8;
    const ushort_t* ks = qkT + ((size_t)bi * NN + srow) * QKLD + 512 + h * HD + g1 * 8;
    const ushort_t* vs = vN + ((size_t)bi * CC + h * HD + srow) * NN + g1 * 8;

    uint4 kr0 = *(const uint4*)(ks);
    uint4 kr1 = *(const uint4*)(ks + 32);
    uint4 vr0 = *(const uint4*)(vs);
    uint4 vr1 = *(const uint4*)(vs + 32);
    {
        ushort_t* kd = &Kt[0][srow * 64];
        *(uint4*)(kd + ko1) = kr0; *(uint4*)(kd + ko2) = kr1;
        ushort_t* vd = &Vn[0][srow * 64];
        *(uint4*)(vd + ko1) = vr0; *(uint4*)(vd + ko2) = vr1;
    }
    kr0 = *(const uint4*)(ks + (size_t)64 * QKLD);
    kr1 = *(const uint4*)(ks + (size_t)64 * QKLD + 32);
    vr0 = *(const uint4*)(vs + 64);
    vr1 = *(const uint4*)(vs + 64 + 32);
    __syncthreads();

    for (int it = 0; it < 16; ++it) {
        int cur = it & 1;
        const ushort_t* KtC = &Kt[cur][0];
        const ushort_t* VnC = &Vn[cur][0];
        if (it < 15) {
            ushort_t* kd = &Kt[cur ^ 1][srow * 64];
            *(uint4*)(kd + ko1) = kr0; *(uint4*)(kd + ko2) = kr1;
            ushort_t* vd = &Vn[cur ^ 1][srow * 64];
            *(uint4*)(vd + ko1) = vr0; *(uint4*)(vd + ko2) = vr1;
        }
        if (it < 14) {
            size_t mo = (size_t)(it + 2) * 64;
            kr0 = *(const uint4*)(ks + mo * QKLD);
            kr1 = *(const uint4*)(ks + mo * QKLD + 32);
            vr0 = *(const uint4*)(vs + mo);
            vr1 = *(const uint4*)(vs + mo + 32);
        }

        floatx4 S[4];
#pragma unroll
        for (int t = 0; t < 4; ++t) {
            const ushort_t* krow = KtC + (t * 16 + ln) * 64;
            bf16x8 b0 = *(const bf16x8*)(krow + ksl0);
            bf16x8 b1 = *(const bf16x8*)(krow + ksl1);
            floatx4 acc = (floatx4){0.f, 0.f, 0.f, 0.f};
            acc = __builtin_amdgcn_mfma_f32_16x16x32_bf16(aq0, b0, acc, 0, 0, 0);
            acc = __builtin_amdgcn_mfma_f32_16x16x32_bf16(aq1, b1, acc, 0, 0, 0);
            S[t] = acc;
        }

#pragma unroll
        for (int t = 0; t < 4; ++t) {
#pragma unroll
            for (int r = 0; r < 4; ++r) {
                float p = exp2f(S[t][r]);
                int qr = qd * 4 + r;
                Pme[qr * 64 + ((t * 2 + lb) ^ (qr & 7)) * 8 + l7] = f2us(p);
            }
        }
        bf16x8 pa0 = *(const bf16x8*)&Pme[ln * 64 + ksl0];
        bf16x8 pa1 = *(const bf16x8*)&Pme[ln * 64 + ksl1];

        lsum = __builtin_amdgcn_mfma_f32_16x16x32_bf16(pa0, ones, lsum, 0, 0, 0);
        lsum = __builtin_amdgcn_mfma_f32_16x16x32_bf16(pa1, ones, lsum, 0, 0, 0);

#pragma unroll
        for (int t = 0; t < 4; ++t) {
            const ushort_t* vrow = VnC + (t * 16 + ln) * 64;
            bf16x8 v0 = *(const bf16x8*)(vrow + ksl0);
            bf16x8 v1 = *(const bf16x8*)(vrow + ksl1);
            O[t] = __builtin_amdgcn_mfma_f32_16x16x32_bf16(pa0, v0, O[t], 0, 0, 0);
            O[t] = __builtin_amdgcn_mfma_f32_16x16x32_bf16(pa1, v1, O[t], 0, 0, 0);
        }
        if (it < 15) __syncthreads();
    }

    float inv[4];
#pragma unroll
    for (int r = 0; r < 4; ++r) inv[r] = 1.f / lsum[r];
#pragma unroll
    for (int t = 0; t < 4; ++t) {
#pragma unroll
        for (int r = 0; r < 4; ++r) {
            int n = q0 + wq * 16 + qd * 4 + r;
            ((ushort_t*)aoT)[((size_t)bi * NN + n) * CC + h * HD + t * 16 + ln] =
                f2us(O[t][r] * inv[r]);
        }
    }
}

// ---------------- Proj GEMM + bias + residual: 64x128 tile, global_load_lds staging.
// Same linear+source-swizzle scheme as qkv. Store epilogue byte-identical to round 6/7.
__global__ __launch_bounds__(256) void proj_gemm(const bf16* __restrict__ aoT,
                                                 const ushort_t* __restrict__ wB,
                                                 const float* __restrict__ bias,
                                                 const float* __restrict__ xres,
                                                 float* __restrict__ out) {
    __shared__ ushort_t Wl[64 * 32];   // [c_out][k] linear, 4 KB
    __shared__ ushort_t Xl[128 * 32];  // [n][k] linear, 8 KB
    int b  = blockIdx.z;
    int o0 = blockIdx.y * 64;
    int n0 = blockIdx.x * 128;
    int tid = threadIdx.x;
    int wv = tid >> 6, l = tid & 63, ln = l & 15, qd = (l >> 4) & 3;
    int wm = wv >> 1, wn = wv & 1;

    // X: wave wv stages rows [32wv, 32wv+32), 2 calls. W: wave wv stages rows [16wv, 16wv+16), 1 call.
    int strow = wv * 32 + (l >> 2);
    int sgran = (l & 3) ^ ((l >> 2) & 3);
    const ushort_t* xsrc = (const ushort_t*)aoT + ((size_t)b * NN + n0 + strow) * CC + sgran * 8;
    int wrow = wv * 16 + (l >> 2);
    const ushort_t* wsrc = wB + (size_t)(o0 + wrow) * CC + sgran * 8;
    ushort_t* xl0 = &Xl[(wv * 32) * 32];
    ushort_t* xl1 = &Xl[(wv * 32 + 16) * 32];
    ushort_t* wl0 = &Wl[(wv * 16) * 32];

    floatx4 acc[2][4];
#pragma unroll
    for (int i = 0; i < 2; ++i)
#pragma unroll
        for (int j = 0; j < 4; ++j) acc[i][j] = (floatx4){0.f, 0.f, 0.f, 0.f};

    int qs = (qd ^ (ln & 3)) * 8;

    for (int k0 = 0; k0 < CC; k0 += 32) {
        GLD16(wsrc + k0, wl0);
        GLD16(xsrc + k0, xl0);
        GLD16(xsrc + k0 + 16 * CC, xl1);
        __syncthreads();
        bf16x8 af[2], bfr[4];
#pragma unroll
        for (int i = 0; i < 2; ++i)
            af[i] = *(const bf16x8*)&Wl[(wm * 32 + i * 16 + ln) * 32 + qs];
#pragma unroll
        for (int j = 0; j < 4; ++j)
            bfr[j] = *(const bf16x8*)&Xl[(wn * 64 + j * 16 + ln) * 32 + qs];
#pragma unroll
        for (int i = 0; i < 2; ++i)
#pragma unroll
            for (int j = 0; j < 4; ++j)
                acc[i][j] = __builtin_amdgcn_mfma_f32_16x16x32_bf16(af[i], bfr[j], acc[i][j], 0, 0, 0);
        __syncthreads();
    }

#pragma unroll
    for (int i = 0; i < 2; ++i) {
#pragma unroll
        for (int r = 0; r < 4; ++r) {
            int o = o0 + wm * 32 + i * 16 + qd * 4 + r;
            float bb = bias[o];
            size_t rb = ((size_t)b * CC + o) * NN + n0 + wn * 64 + ln;
#pragma unroll
            for (int j = 0; j < 4; ++j)
                out[rb + j * 16] = acc[i][j][r] + bb + xres[rb + j * 16];
        }
    }
}

extern "C" void kernel_launch(void* const* d_in, const int* in_sizes, int n_in,
                              void* d_out, int out_size, void* d_ws, size_t ws_size,
                              hipStream_t stream) {
    const float* x      = (const float*)d_in[0];
    const float* gamma  = (const float*)d_in[1];
    const float* beta   = (const float*)d_in[2];
    const float* w_qkv  = (const float*)d_in[3];
    const float* b_qkv  = (const float*)d_in[4];
    const float* w_proj = (const float*)d_in[5];
    const float* b_proj = (const float*)d_in[6];
    float* out = (float*)d_out;

    // Workspace (bf16): xnT 8 MB | qkT 16 MB | vN 8 MB | wqkvB 1.5 MB | wprojB 0.5 MB.
    bf16* xnT = (bf16*)d_ws;                       // [b][n][c]
    bf16* qkT = xnT + (size_t)BB * CC * NN;        // [b][n][1024] (Q|K)
    bf16* vN  = qkT + (size_t)BB * NN * QKLD;      // [b][c][n]
    ushort_t* wqkvB  = (ushort_t*)(vN + (size_t)BB * CC * NN);  // [1536][512] bf16
    ushort_t* wprojB = wqkvB + (size_t)C3 * CC;                 // [512][512] bf16
    bf16* aoT = xnT;                               // [b][n][c], reuse

    gn_kernel<<<BB * NG + 256, 256, 0, stream>>>(x, gamma, beta, xnT,
                                                 w_qkv, w_proj, wqkvB, wprojB);
    qkv_gemm<<<dim3(NN / 128, C3 / 128, BB), 256, 0, stream>>>(wqkvB, xnT, b_qkv, qkT, vN);
    attn_kernel<<<dim3(NH, NN / 64, BB), 256, 0, stream>>>(qkT, vN, aoT);
    proj_gemm<<<dim3(NN / 128, CC / 64, BB), 256, 0, stream>>>(aoT, wprojB, b_proj, x, out);
}